// Round 17
// baseline (1815.467 us; speedup 1.0000x reference)
//
#include <hip/hip_runtime.h>
#include <math.h>
#include <cstddef>

// GPT-2 small forward: L=12 H=12 C=768 D=64 V=50257, B=2 T=1024 (M=2048)
// Round 17: revert round-16 split-K (neutral: partial-traffic offset the
// occupancy gain) back to round-15 structure (best, 1787us). One change:
// attention K/V LDS double-buffer -> ONE barrier per KV-tile (was two);
// reg-preload (T14) kept. Everything else identical to round 15.

#define Cdim 768
#define Hn   12
#define Ln   12
#define Tn   1024
#define Bn   2
#define Mrows (Bn * Tn)

typedef unsigned short ushort_t;
typedef __bf16 bf16x8 __attribute__((ext_vector_type(8)));
typedef float  f32x4  __attribute__((ext_vector_type(4)));

__device__ __forceinline__ ushort_t f2bf(float v) {
    union { float f; unsigned int u; } x; x.f = v;
    unsigned int r = x.u + 0x7fffu + ((x.u >> 16) & 1u);   // RNE
    return (ushort_t)(r >> 16);
}
__device__ __forceinline__ float gelu_f(float v) {
    return 0.5f * v * (1.0f + erff(v * 0.70710678118654752f));
}
__device__ __forceinline__ void gload16(const void* g, void* l) {
    __builtin_amdgcn_global_load_lds(
        (const __attribute__((address_space(1))) unsigned int*)g,
        (__attribute__((address_space(3))) unsigned int*)l, 16, 0, 0);
}

// ---------------- embedding ----------------
__global__ void embed_k(const int* __restrict__ idx, const float* __restrict__ wte,
                        const float* __restrict__ wpe, float* __restrict__ x) {
    int i = blockIdx.x * 256 + threadIdx.x;
    int c  = i % Cdim;
    int bt = i / Cdim;
    int t  = bt % Tn;
    int tok = idx[bt];
    x[i] = wte[(size_t)tok * Cdim + c] + wpe[(size_t)t * Cdim + c];
}

// ---------------- layer norm -> bf16 ----------------
__global__ __launch_bounds__(256) void ln_k(const float* __restrict__ x,
                                            const float* __restrict__ w,
                                            const float* __restrict__ b,
                                            ushort_t* __restrict__ out) {
    int row = blockIdx.x;
    const float* xr = x + (size_t)row * Cdim;
    int t = threadIdx.x;
    float v0 = xr[t], v1 = xr[t + 256], v2 = xr[t + 512];
    float s = v0 + v1 + v2;
    #pragma unroll
    for (int o = 32; o > 0; o >>= 1) s += __shfl_xor(s, o);
    __shared__ float red[8];
    int wid = t >> 6;
    if ((t & 63) == 0) red[wid] = s;
    __syncthreads();
    float mean = (red[0] + red[1] + red[2] + red[3]) * (1.0f / 768.0f);
    float d0 = v0 - mean, d1 = v1 - mean, d2 = v2 - mean;
    float sq = d0 * d0 + d1 * d1 + d2 * d2;
    #pragma unroll
    for (int o = 32; o > 0; o >>= 1) sq += __shfl_xor(sq, o);
    if ((t & 63) == 0) red[4 + wid] = sq;
    __syncthreads();
    float var = (red[4] + red[5] + red[6] + red[7]) * (1.0f / 768.0f);
    float rstd = rsqrtf(var + 1e-5f);
    ushort_t* orow = out + (size_t)row * Cdim;
    orow[t]       = f2bf(d0 * rstd * w[t]       + b[t]);
    orow[t + 256] = f2bf(d1 * rstd * w[t + 256] + b[t + 256]);
    orow[t + 512] = f2bf(d2 * rstd * w[t + 512] + b[t + 512]);
}

// ---------------- 32x32 transpose+cast tile helper ----------------
__device__ __forceinline__ void tconv_tile(const float* __restrict__ W,
                                           ushort_t* __restrict__ WT,
                                           int K, int N, int n0, int k0, bool guard) {
    __shared__ float t[32][33];
    int x = threadIdx.x & 31, y = threadIdx.x >> 5;
    #pragma unroll
    for (int j = 0; j < 4; ++j) {
        int kk = k0 + y + j * 8, nn = n0 + x;
        t[y + j * 8][x] = (!guard || nn < N) ? W[(size_t)kk * N + nn] : 0.0f;
    }
    __syncthreads();
    #pragma unroll
    for (int j = 0; j < 4; ++j) {
        int nn = n0 + y + j * 8, kk = k0 + x;
        WT[(size_t)nn * K + kk] = f2bf(t[x][y + j * 8]);
    }
}

// LM head conversion (N guard / zero-pad)
__global__ __launch_bounds__(256) void wconv_k(const float* __restrict__ W,
                                               ushort_t* __restrict__ WT,
                                               int K, int N) {
    tconv_tile(W, WT, K, N, blockIdx.x * 32, blockIdx.y * 32, true);
}

// ---- per-layer conversion body ----
__device__ __forceinline__ void conv_body(
    int bid,
    const float* Wq, const float* Wk, const float* Wv, const float* Wo,
    const float* Wfc, const float* Wpr,
    const float* bq, const float* bk, const float* bv,
    ushort_t* wqkvt, ushort_t* wot, ushort_t* wfct, ushort_t* wprt,
    float* bqkv) {
    if (bid < 2304) {
        int z = bid / 576, t = bid % 576;
        const float* W = (z == 0) ? Wq : (z == 1) ? Wk : (z == 2) ? Wv : Wo;
        ushort_t* dst = (z < 3) ? (wqkvt + (size_t)z * 768 * 768) : wot;
        tconv_tile(W, dst, 768, 768, (t % 24) * 32, (t / 24) * 32, false);
    } else if (bid < 4608) {
        int t = bid - 2304;
        tconv_tile(Wfc, wfct, 768, 3072, (t % 96) * 32, (t / 96) * 32, false);
    } else if (bid < 6912) {
        int t = bid - 4608;
        tconv_tile(Wpr, wprt, 3072, 768, (t % 24) * 32, (t / 24) * 32, false);
    } else {
        int i = (bid - 6912) * 256 + threadIdx.x;
        bqkv[i] = (i < 768) ? bq[i] : (i < 1536 ? bk[i - 768] : bv[i - 1536]);
    }
}

__global__ __launch_bounds__(256) void conv_layer_k(
    const float* Wq, const float* Wk, const float* Wv, const float* Wo,
    const float* Wfc, const float* Wpr,
    const float* bq, const float* bk, const float* bv,
    ushort_t* wqkvt, ushort_t* wot, ushort_t* wfct, ushort_t* wprt,
    float* bqkv) {
    conv_body(blockIdx.x, Wq, Wk, Wv, Wo, Wfc, Wpr, bq, bk, bv,
              wqkvt, wot, wfct, wprt, bqkv);
}

// all 12 layers in one launch; grid = 12 * 6921
__global__ __launch_bounds__(256) void conv_all_k(
    const float* Wq, const float* Wk, const float* Wv, const float* Wo,
    const float* Wfc, const float* Wpr,
    const float* bq, const float* bk, const float* bv,
    ushort_t* wqkvt, ushort_t* wot, ushort_t* wfct, ushort_t* wprt,
    float* bqkv) {
    int l = blockIdx.x / 6921, bid = blockIdx.x % 6921;
    const size_t o2 = (size_t)l * 768 * 768;
    const size_t o4 = (size_t)l * 768 * 3072;
    conv_body(bid,
              Wq + o2, Wk + o2, Wv + o2, Wo + o2, Wfc + o4, Wpr + o4,
              bq + l * 768, bk + l * 768, bv + l * 768,
              wqkvt + (size_t)l * 2304 * 768, wot + o2,
              wfct + o4, wprt + o4, bqkv + l * 2304);
}

// ======== generalized deep-prefetch counted-vmcnt MFMA GEMM template ========
// BK=64; LDS slot swizzle logical^(row&7), both-sides (0 bank conflicts).
// Stage ALL loads of kt+1 (full-tile latency lead), counted vmcnt (never
// drain in loop), raw barriers, setprio. QKV: scattered epilogue.
template <int BM, int BN, int TH, int WGN,
          bool BIAS, bool GELU_, bool RES, bool OUTBF16, bool XCD, bool QKV>
__global__ __launch_bounds__(TH, 2) void gemm_pipe_k(
    const ushort_t* __restrict__ A,    // [M][K] bf16
    const ushort_t* __restrict__ Bt,   // [Npad][K] bf16
    const float* __restrict__ bias,
    const float* __restrict__ res,     // [M][N] fp32 (RES only)
    void* __restrict__ Cout,
    ushort_t* __restrict__ kdst,       // QKV only
    ushort_t* __restrict__ vdst,       // QKV only
    int M, int N, int K, int cpx, int mtiles) {
    constexpr int SA = BM * 128;
    constexpr int SB = BN * 128;
    constexpr int WM = BM / 2;
    constexpr int WN = BN / WGN;
    constexpr int FM = WM / 16;
    constexpr int FN = WN / 16;
    constexpr int RJ = TH / 8;
    constexpr int JA = BM / RJ;
    constexpr int JB = BN / RJ;
    constexpr int NL = JA + JB;
    static_assert(NL == 4 || NL == 6 || NL == 8, "vmcnt immediate");
    __shared__ char lds[2 * (SA + SB)];
    char* Abase = lds;
    char* Bbase = lds + 2 * SA;

    const int tid = threadIdx.x;
    const int lane = tid & 63;
    const int w = tid >> 6;
    const int wr = w / WGN, wc = w % WGN;
    int m0, n0;
    if (XCD) {
        int lid = ((int)blockIdx.x & 7) * cpx + ((int)blockIdx.x >> 3);
        m0 = (lid % mtiles) * BM;
        n0 = (lid / mtiles) * BN;
    } else {
        m0 = blockIdx.y * BM;
        n0 = blockIdx.x * BN;
    }

    f32x4 acc[FM][FN] = {};

    const int srowl = tid >> 3;
    const int sslot = (tid & 7) ^ (srowl & 7);
    const ushort_t* Asrc = A  + (size_t)(m0 + srowl) * K + sslot * 8;
    const ushort_t* Bsrc = Bt + (size_t)(n0 + srowl) * K + sslot * 8;

    auto stageall = [&](int d, int kt) {
        const ushort_t* As = Asrc + kt * 64;
        const ushort_t* Bs = Bsrc + kt * 64;
        #pragma unroll
        for (int j = 0; j < JA; ++j)
            gload16(As + (size_t)(j * RJ) * K, Abase + d * SA + tid * 16 + j * (TH * 16));
        #pragma unroll
        for (int j = 0; j < JB; ++j)
            gload16(Bs + (size_t)(j * RJ) * K, Bbase + d * SB + tid * 16 + j * (TH * 16));
    };
    auto readA = [&](int d, int m, int ks) -> bf16x8 {
        int rl = wr * WM + m * 16 + (lane & 15);
        int s  = ks * 4 + (lane >> 4);
        return *(const bf16x8*)(Abase + d * SA + rl * 128 + ((s ^ (rl & 7)) << 4));
    };
    auto readB = [&](int d, int n, int ks) -> bf16x8 {
        int rl = wc * WN + n * 16 + (lane & 15);
        int s  = ks * 4 + (lane >> 4);
        return *(const bf16x8*)(Bbase + d * SB + rl * 128 + ((s ^ (rl & 7)) << 4));
    };

    const int nt = K >> 6;
    stageall(0, 0);
    for (int kt = 0; kt < nt; ++kt) {
        const int d = kt & 1;
        if (kt + 1 < nt) {
            stageall(d ^ 1, kt + 1);
            if constexpr (NL == 8)      asm volatile("s_waitcnt vmcnt(8)" ::: "memory");
            else if constexpr (NL == 6) asm volatile("s_waitcnt vmcnt(6)" ::: "memory");
            else                        asm volatile("s_waitcnt vmcnt(4)" ::: "memory");
        } else {
            asm volatile("s_waitcnt vmcnt(0)" ::: "memory");
        }
        __builtin_amdgcn_s_barrier();
        asm volatile("" ::: "memory");

        bf16x8 bfr[FN][2];
        #pragma unroll
        for (int n = 0; n < FN; ++n) {
            bfr[n][0] = readB(d, n, 0);
            bfr[n][1] = readB(d, n, 1);
        }
        __builtin_amdgcn_s_setprio(1);
        #pragma unroll
        for (int m = 0; m < FM; ++m) {
            bf16x8 a0 = readA(d, m, 0);
            bf16x8 a1 = readA(d, m, 1);
            #pragma unroll
            for (int n = 0; n < FN; ++n) {
                acc[m][n] = __builtin_amdgcn_mfma_f32_16x16x32_bf16(
                    a0, bfr[n][0], acc[m][n], 0, 0, 0);
                acc[m][n] = __builtin_amdgcn_mfma_f32_16x16x32_bf16(
                    a1, bfr[n][1], acc[m][n], 0, 0, 0);
            }
        }
        __builtin_amdgcn_s_setprio(0);
        asm volatile("" ::: "memory");
        __builtin_amdgcn_s_barrier();
    }

    const int r0 = (lane >> 4) * 4, c0 = lane & 15;
    if constexpr (QKV) {
        const int region = n0 / 768;
        #pragma unroll
        for (int m = 0; m < FM; ++m)
            #pragma unroll
            for (int n = 0; n < FN; ++n) {
                int col = n0 + wc * WN + n * 16 + c0;
                int row0 = m0 + wr * WM + m * 16 + r0;
                float vv[4];
                #pragma unroll
                for (int q = 0; q < 4; ++q) vv[q] = acc[m][n][q] + bias[col];
                if (region == 0) {
                    #pragma unroll
                    for (int q = 0; q < 4; ++q)
                        ((ushort_t*)Cout)[(size_t)(row0 + q) * 768 + col] = f2bf(vv[q]);
                } else if (region == 1) {
                    int ck = col - 768, h = ck >> 6, dd = ck & 63;
                    #pragma unroll
                    for (int q = 0; q < 4; ++q) {
                        int row = row0 + q;
                        kdst[(((size_t)(row >> 10) * Hn + h) * Tn + (row & 1023)) * 64 + dd]
                            = f2bf(vv[q]);
                    }
                } else {
                    int cv = col - 1536, h = cv >> 6, dd = cv & 63;
                    int bb = row0 >> 10, tok = row0 & 1023;
                    ushort4 pk;
                    pk.x = f2bf(vv[0]); pk.y = f2bf(vv[1]);
                    pk.z = f2bf(vv[2]); pk.w = f2bf(vv[3]);
                    *(ushort4*)&vdst[(((size_t)bb * Hn + h) * 64 + dd) * Tn + tok] = pk;
                }
            }
        return;
    }
    #pragma unroll
    for (int m = 0; m < FM; ++m)
        #pragma unroll
        for (int n = 0; n < FN; ++n) {
            int col = n0 + wc * WN + n * 16 + c0;
            if (col < N) {
                #pragma unroll
                for (int q = 0; q < 4; ++q) {
                    int row = m0 + wr * WM + m * 16 + r0 + q;
                    float v = acc[m][n][q];
                    if (BIAS) v += bias[col];
                    if (GELU_) v = gelu_f(v);
                    if (RES) v += res[(size_t)row * N + col];
                    if (OUTBF16) ((ushort_t*)Cout)[(size_t)row * N + col] = f2bf(v);
                    else         ((float*)Cout)[(size_t)row * N + col] = v;
                }
            }
        }
}

// --- MFMA flash attention: T14 reg-preload + LDS double-buffer (1 barrier) ---
__global__ __launch_bounds__(256) void attn_mfma_k(
    const ushort_t* __restrict__ qb,
    const ushort_t* __restrict__ kpb,
    const ushort_t* __restrict__ vtb,
    ushort_t* __restrict__ yb) {
    __shared__ ushort_t Ks[2][64][72];
    __shared__ ushort_t Vt[2][64][72];
    __shared__ ushort_t Pl[4][16][72];
    const int chunk = (Tn / 64 - 1) - blockIdx.x;
    const int h = blockIdx.y, b = blockIdx.z;
    const int tid = threadIdx.x, lane = tid & 63, w = tid >> 6;
    const int c = lane & 15, g = lane >> 4;
    const int qrow0 = chunk * 64 + w * 16;

    const ushort_t* qp = qb + (size_t)(b * Tn + qrow0 + c) * Cdim + h * 64 + g * 8;
    bf16x8 qa0 = *(const bf16x8*)qp;
    bf16x8 qa1 = *(const bf16x8*)(qp + 32);

    f32x4 accO[4] = {};
    float mrun[4], lrun[4];
    #pragma unroll
    for (int q = 0; q < 4; ++q) { mrun[q] = -1e30f; lrun[q] = 0.0f; }

    const int skey = tid >> 2, sd0 = (tid & 3) * 16;
    const ushort_t* ksrc = kpb + ((size_t)(b * Hn + h) * Tn + skey) * 64 + sd0;
    const int vd = tid >> 2, vseg = tid & 3;
    const ushort_t* vsrc = vtb + ((size_t)(b * Hn + h) * 64 + vd) * Tn + vseg * 16;

    uint4 kr0, kr1, vr0, vr1;
    auto loadt = [&](int kt) {
        const ushort_t* kp = ksrc + (size_t)kt * 64 * 64;
        kr0 = *(const uint4*)kp;
        kr1 = *(const uint4*)(kp + 8);
        const ushort_t* vp = vsrc + kt * 64;
        vr0 = *(const uint4*)vp;
        vr1 = *(const uint4*)(vp + 8);
    };
    auto storet = [&](int d) {
        *(uint4*)&Ks[d][skey][sd0]     = kr0;
        *(uint4*)&Ks[d][skey][sd0 + 8] = kr1;
        *(uint4*)&Vt[d][vd][vseg * 16]     = vr0;
        *(uint4*)&Vt[d][vd][vseg * 16 + 8] = vr1;
    };

    const int ntiles = chunk + 1;
    loadt(0);
    storet(0);
    __syncthreads();                       // publish tile 0
    for (int kt = 0; kt < ntiles; ++kt) {
        const int d = kt & 1;
        if (kt + 1 < ntiles) loadt(kt + 1);    // HBM latency hides under compute

        f32x4 sf[4];
        #pragma unroll
        for (int nk = 0; nk < 4; ++nk) {
            bf16x8 kf0 = *(const bf16x8*)&Ks[d][nk * 16 + c][g * 8];
            bf16x8 kf1 = *(const bf16x8*)&Ks[d][nk * 16 + c][g * 8 + 32];
            f32x4 z = {};
            z = __builtin_amdgcn_mfma_f32_16x16x32_bf16(qa0, kf0, z, 0, 0, 0);
            z = __builtin_amdgcn_mfma_f32_16x16x32_bf16(qa1, kf1, z, 0, 0, 0);
            sf[nk] = z;
        }
        float pmax[4] = {-1e30f, -1e30f, -1e30f, -1e30f};
        #pragma unroll
        for (int nk = 0; nk < 4; ++nk) {
            int key = kt * 64 + nk * 16 + c;
            #pragma unroll
            for (int q = 0; q < 4; ++q) {
                float sv = sf[nk][q];
                int row = qrow0 + g * 4 + q;
                sv = (key > row) ? -1e30f : sv;
                sf[nk][q] = sv;
                pmax[q] = fmaxf(pmax[q], sv);
            }
        }
        #pragma unroll
        for (int q = 0; q < 4; ++q)
            #pragma unroll
            for (int off = 1; off < 16; off <<= 1)
                pmax[q] = fmaxf(pmax[q], __shfl_xor(pmax[q], off));
        float corr[4], psum[4];
        #pragma unroll
        for (int q = 0; q < 4; ++q) {
            float mn = fmaxf(mrun[q], pmax[q]);
            corr[q] = __expf((mrun[q] - mn) * 0.125f);
            mrun[q] = mn;
            psum[q] = 0.0f;
        }
        #pragma unroll
        for (int nk = 0; nk < 4; ++nk)
            #pragma unroll
            for (int q = 0; q < 4; ++q) {
                float p = __expf((sf[nk][q] - mrun[q]) * 0.125f);
                psum[q] += p;
                Pl[w][g * 4 + q][nk * 16 + c] = f2bf(p);
            }
        #pragma unroll
        for (int q = 0; q < 4; ++q) {
            #pragma unroll
            for (int off = 1; off < 16; off <<= 1)
                psum[q] += __shfl_xor(psum[q], off);
            lrun[q] = lrun[q] * corr[q] + psum[q];
        }
        #pragma unroll
        for (int ni = 0; ni < 4; ++ni)
            #pragma unroll
            for (int q = 0; q < 4; ++q)
                accO[ni][q] *= corr[q];

        asm volatile("" ::: "memory");   // wave-local Pl write->read order
        bf16x8 pa0 = *(const bf16x8*)&Pl[w][c][g * 8];
        bf16x8 pa1 = *(const bf16x8*)&Pl[w][c][g * 8 + 32];
        #pragma unroll
        for (int ni = 0; ni < 4; ++ni) {
            bf16x8 bv0 = *(const bf16x8*)&Vt[d][ni * 16 + c][g * 8];
            bf16x8 bv1 = *(const bf16x8*)&Vt[d][ni * 16 + c][g * 8 + 32];
            accO[ni] = __builtin_amdgcn_mfma_f32_16x16x32_bf16(pa0, bv0, accO[ni], 0, 0, 0);
            accO[ni] = __builtin_amdgcn_mfma_f32_16x16x32_bf16(pa1, bv1, accO[ni], 0, 0, 0);
        }

        if (kt + 1 < ntiles) {
            storet(d ^ 1);               // buf^1's last readers (kt-1) done
            __syncthreads();             // publish kt+1; retire kt
        }
    }

    #pragma unroll
    for (int q = 0; q < 4; ++q) {
        float inv = 1.0f / lrun[q];
        ushort_t* yr = yb + (size_t)(b * Tn + qrow0 + g * 4 + q) * Cdim + h * 64;
        #pragma unroll
        for (int ni = 0; ni < 4; ++ni)
            yr[ni * 16 + c] = f2bf(accO[ni][q] * inv);
    }
}

extern "C" void kernel_launch(void* const* d_in, const int* in_sizes, int n_in,
                              void* d_out, int out_size, void* d_ws, size_t ws_size,
                              hipStream_t stream) {
    const int*   idx  = (const int*)d_in[0];
    const float* wte  = (const float*)d_in[1];
    const float* wpe  = (const float*)d_in[2];
    const float* ln1w = (const float*)d_in[3];
    const float* ln1b = (const float*)d_in[4];
    const float* Wq   = (const float*)d_in[5];
    const float* bq   = (const float*)d_in[6];
    const float* Wk   = (const float*)d_in[7];
    const float* bk   = (const float*)d_in[8];
    const float* Wv   = (const float*)d_in[9];
    const float* bv   = (const float*)d_in[10];
    const float* Wo   = (const float*)d_in[11];
    const float* bo   = (const float*)d_in[12];
    const float* ln2w = (const float*)d_in[13];
    const float* ln2b = (const float*)d_in[14];
    const float* Wfc  = (const float*)d_in[15];
    const float* bfc  = (const float*)d_in[16];
    const float* Wpr  = (const float*)d_in[17];
    const float* bpr  = (const float*)d_in[18];
    const float* lnfw = (const float*)d_in[19];
    const float* lnfb = (const float*)d_in[20];
    const float* Wlm  = (const float*)d_in[21];
    float* out = (float*)d_out;

    const int M = Mrows;                        // 2048
    const int V = out_size / M;                 // 50257
    const int Vpad = ((V + 255) / 256) * 256;   // 50432

    const size_t SZ_QKV = (size_t)2304 * 768;
    const size_t SZ_O   = (size_t)768 * 768;
    const size_t SZ_FC  = (size_t)3072 * 768;
    const size_t SZ_PR  = (size_t)768 * 3072;
    const size_t SZ_L   = SZ_QKV + SZ_O + SZ_FC + SZ_PR;

    float*    x     = (float*)d_ws;                       // M*C fp32
    float*    bqkvb = x + (size_t)M * Cdim;               // 12*2304 fp32
    ushort_t* qb    = (ushort_t*)(bqkvb + 12 * 2304);     // M*768
    ushort_t* kpb   = qb + (size_t)M * Cdim;              // [B*H][Tn][64]
    ushort_t* vtb   = kpb + (size_t)Bn * Hn * Tn * 64;    // [B*H][64][Tn]
    ushort_t* hb    = vtb + (size_t)Bn * Hn * 64 * Tn;
    ushort_t* yb    = hb + (size_t)M * Cdim;
    ushort_t* mid   = yb + (size_t)M * Cdim;              // M*3072
    ushort_t* wlmt  = mid + (size_t)M * 3072;             // [Vpad][768]
    ushort_t* wbase = wlmt + (size_t)Vpad * Cdim;         // layer weights

    const size_t used_common = (size_t)((char*)wbase - (char*)d_ws);
    const bool big = ws_size >= used_common + 12 * SZ_L * sizeof(ushort_t);

    embed_k<<<(M * Cdim) / 256, 256, 0, stream>>>(idx, wte, wpe, x);
    wconv_k<<<dim3(Vpad / 32, 24), 256, 0, stream>>>(Wlm, wlmt, Cdim, V);

    ushort_t* wqkvt0 = wbase;
    ushort_t* wot0   = wqkvt0 + SZ_QKV;
    ushort_t* wfct0  = wot0 + SZ_O;
    ushort_t* wprt0  = wfct0 + SZ_FC;

    if (big) {
        ushort_t* qkvt_all = wbase;
        ushort_t* ot_all   = qkvt_all + 12 * SZ_QKV;
        ushort_t* fct_all  = ot_all + 12 * SZ_O;
        ushort_t* prt_all  = fct_all + 12 * SZ_FC;
        conv_all_k<<<12 * 6921, 256, 0, stream>>>(
            Wq, Wk, Wv, Wo, Wfc, Wpr, bq, bk, bv,
            qkvt_all, ot_all, fct_all, prt_all, bqkvb);
        for (int l = 0; l < Ln; ++l) {
            ushort_t* wqkvt = qkvt_all + (size_t)l * SZ_QKV;
            ushort_t* wot   = ot_all   + (size_t)l * SZ_O;
            ushort_t* wfct  = fct_all  + (size_t)l * SZ_FC;
            ushort_t* wprt  = prt_all  + (size_t)l * SZ_PR;
            float*    bqkv  = bqkvb + l * 2304;
            ln_k<<<M, 256, 0, stream>>>(x, ln1w + l * Cdim, ln1b + l * Cdim, hb);
            gemm_pipe_k<128, 64, 256, 2, true, false, false, true, false, true>
                <<<dim3(36, 16), 256, 0, stream>>>(
                hb, wqkvt, bqkv, nullptr, qb, kpb, vtb, M, 2304, Cdim, 0, 0);
            attn_mfma_k<<<dim3(16, Hn, Bn), 256, 0, stream>>>(qb, kpb, vtb, yb);
            gemm_pipe_k<64, 64, 256, 2, true, false, true, false, false, false>
                <<<dim3(12, 32), 256, 0, stream>>>(
                yb, wot, bo + l * Cdim, x, x, nullptr, nullptr, M, Cdim, Cdim, 0, 0);
            ln_k<<<M, 256, 0, stream>>>(x, ln2w + l * Cdim, ln2b + l * Cdim, hb);
            gemm_pipe_k<128, 64, 256, 2, true, true, false, true, false, false>
                <<<dim3(48, 16), 256, 0, stream>>>(
                hb, wfct, bfc + (size_t)l * 4 * Cdim, nullptr, mid,
                nullptr, nullptr, M, 3072, Cdim, 0, 0);
            gemm_pipe_k<64, 64, 256, 2, true, false, true, false, false, false>
                <<<dim3(12, 32), 256, 0, stream>>>(
                mid, wprt, bpr + l * Cdim, x, x, nullptr, nullptr, M, Cdim, 3072, 0, 0);
        }
    } else {
        for (int l = 0; l < Ln; ++l) {
            const size_t wo2 = (size_t)l * Cdim * Cdim;
            const size_t wo4 = (size_t)l * Cdim * 4 * Cdim;
            conv_layer_k<<<6921, 256, 0, stream>>>(
                Wq + wo2, Wk + wo2, Wv + wo2, Wo + wo2, Wfc + wo4, Wpr + wo4,
                bq + l * Cdim, bk + l * Cdim, bv + l * Cdim,
                wqkvt0, wot0, wfct0, wprt0, bqkvb);
            ln_k<<<M, 256, 0, stream>>>(x, ln1w + l * Cdim, ln1b + l * Cdim, hb);
            gemm_pipe_k<128, 64, 256, 2, true, false, false, true, false, true>
                <<<dim3(36, 16), 256, 0, stream>>>(
                hb, wqkvt0, bqkvb, nullptr, qb, kpb, vtb, M, 2304, Cdim, 0, 0);
            attn_mfma_k<<<dim3(16, Hn, Bn), 256, 0, stream>>>(qb, kpb, vtb, yb);
            gemm_pipe_k<64, 64, 256, 2, true, false, true, false, false, false>
                <<<dim3(12, 32), 256, 0, stream>>>(
                yb, wot0, bo + l * Cdim, x, x, nullptr, nullptr, M, Cdim, Cdim, 0, 0);
            ln_k<<<M, 256, 0, stream>>>(x, ln2w + l * Cdim, ln2b + l * Cdim, hb);
            gemm_pipe_k<128, 64, 256, 2, true, true, false, true, false, false>
                <<<dim3(48, 16), 256, 0, stream>>>(
                hb, wfct0, bfc + (size_t)l * 4 * Cdim, nullptr, mid,
                nullptr, nullptr, M, 3072, Cdim, 0, 0);
            gemm_pipe_k<64, 64, 256, 2, true, false, true, false, false, false>
                <<<dim3(12, 32), 256, 0, stream>>>(
                mid, wprt0, bpr + l * Cdim, x, x, nullptr, nullptr, M, Cdim, 3072, 0, 0);
        }
    }

    ln_k<<<M, 256, 0, stream>>>(x, lnfw, lnfb, hb);
    // LM head: round-13 optimum -- 128x128 tiles, XCD strips (6304 = 8 x 788,
    // M-fastest, mtiles=16), regular fp32 stores.
    const int nblk = 16 * (Vpad / 128);         // 6304
    gemm_pipe_k<128, 128, 256, 2, false, false, false, false, true, false>
        <<<nblk, 256, 0, stream>>>(
        hb, wlmt, nullptr, nullptr, out, nullptr, nullptr, M, V, Cdim, nblk / 8, 16);
}

// Round 18
// 1782.185 us; speedup vs baseline: 1.0187x; 1.0187x over previous
//
#include <hip/hip_runtime.h>
#include <math.h>
#include <cstddef>

// GPT-2 small forward: L=12 H=12 C=768 D=64 V=50257, B=2 T=1024 (M=2048)
// Round 18: exact revert to round-15 best (1787us). Round-16 split-K and
// round-17 attn double-buffer both measured neutral/negative -> plateau.
// Structure: counted-vmcnt deep-prefetch GEMM template (3-bit both-sides LDS
// swizzle, 0 bank conflicts), fused QKV epilogue, T14 single-buffer attn,
// LM head at 128x128 XCD-strip optimum, single all-layer weight conversion.

#define Cdim 768
#define Hn   12
#define Ln   12
#define Tn   1024
#define Bn   2
#define Mrows (Bn * Tn)

typedef unsigned short ushort_t;
typedef __bf16 bf16x8 __attribute__((ext_vector_type(8)));
typedef float  f32x4  __attribute__((ext_vector_type(4)));

__device__ __forceinline__ ushort_t f2bf(float v) {
    union { float f; unsigned int u; } x; x.f = v;
    unsigned int r = x.u + 0x7fffu + ((x.u >> 16) & 1u);   // RNE
    return (ushort_t)(r >> 16);
}
__device__ __forceinline__ float gelu_f(float v) {
    return 0.5f * v * (1.0f + erff(v * 0.70710678118654752f));
}
__device__ __forceinline__ void gload16(const void* g, void* l) {
    __builtin_amdgcn_global_load_lds(
        (const __attribute__((address_space(1))) unsigned int*)g,
        (__attribute__((address_space(3))) unsigned int*)l, 16, 0, 0);
}

// ---------------- embedding ----------------
__global__ void embed_k(const int* __restrict__ idx, const float* __restrict__ wte,
                        const float* __restrict__ wpe, float* __restrict__ x) {
    int i = blockIdx.x * 256 + threadIdx.x;
    int c  = i % Cdim;
    int bt = i / Cdim;
    int t  = bt % Tn;
    int tok = idx[bt];
    x[i] = wte[(size_t)tok * Cdim + c] + wpe[(size_t)t * Cdim + c];
}

// ---------------- layer norm -> bf16 ----------------
__global__ __launch_bounds__(256) void ln_k(const float* __restrict__ x,
                                            const float* __restrict__ w,
                                            const float* __restrict__ b,
                                            ushort_t* __restrict__ out) {
    int row = blockIdx.x;
    const float* xr = x + (size_t)row * Cdim;
    int t = threadIdx.x;
    float v0 = xr[t], v1 = xr[t + 256], v2 = xr[t + 512];
    float s = v0 + v1 + v2;
    #pragma unroll
    for (int o = 32; o > 0; o >>= 1) s += __shfl_xor(s, o);
    __shared__ float red[8];
    int wid = t >> 6;
    if ((t & 63) == 0) red[wid] = s;
    __syncthreads();
    float mean = (red[0] + red[1] + red[2] + red[3]) * (1.0f / 768.0f);
    float d0 = v0 - mean, d1 = v1 - mean, d2 = v2 - mean;
    float sq = d0 * d0 + d1 * d1 + d2 * d2;
    #pragma unroll
    for (int o = 32; o > 0; o >>= 1) sq += __shfl_xor(sq, o);
    if ((t & 63) == 0) red[4 + wid] = sq;
    __syncthreads();
    float var = (red[4] + red[5] + red[6] + red[7]) * (1.0f / 768.0f);
    float rstd = rsqrtf(var + 1e-5f);
    ushort_t* orow = out + (size_t)row * Cdim;
    orow[t]       = f2bf(d0 * rstd * w[t]       + b[t]);
    orow[t + 256] = f2bf(d1 * rstd * w[t + 256] + b[t + 256]);
    orow[t + 512] = f2bf(d2 * rstd * w[t + 512] + b[t + 512]);
}

// ---------------- 32x32 transpose+cast tile helper ----------------
__device__ __forceinline__ void tconv_tile(const float* __restrict__ W,
                                           ushort_t* __restrict__ WT,
                                           int K, int N, int n0, int k0, bool guard) {
    __shared__ float t[32][33];
    int x = threadIdx.x & 31, y = threadIdx.x >> 5;
    #pragma unroll
    for (int j = 0; j < 4; ++j) {
        int kk = k0 + y + j * 8, nn = n0 + x;
        t[y + j * 8][x] = (!guard || nn < N) ? W[(size_t)kk * N + nn] : 0.0f;
    }
    __syncthreads();
    #pragma unroll
    for (int j = 0; j < 4; ++j) {
        int nn = n0 + y + j * 8, kk = k0 + x;
        WT[(size_t)nn * K + kk] = f2bf(t[x][y + j * 8]);
    }
}

// LM head conversion (N guard / zero-pad)
__global__ __launch_bounds__(256) void wconv_k(const float* __restrict__ W,
                                               ushort_t* __restrict__ WT,
                                               int K, int N) {
    tconv_tile(W, WT, K, N, blockIdx.x * 32, blockIdx.y * 32, true);
}

// ---- per-layer conversion body ----
__device__ __forceinline__ void conv_body(
    int bid,
    const float* Wq, const float* Wk, const float* Wv, const float* Wo,
    const float* Wfc, const float* Wpr,
    const float* bq, const float* bk, const float* bv,
    ushort_t* wqkvt, ushort_t* wot, ushort_t* wfct, ushort_t* wprt,
    float* bqkv) {
    if (bid < 2304) {
        int z = bid / 576, t = bid % 576;
        const float* W = (z == 0) ? Wq : (z == 1) ? Wk : (z == 2) ? Wv : Wo;
        ushort_t* dst = (z < 3) ? (wqkvt + (size_t)z * 768 * 768) : wot;
        tconv_tile(W, dst, 768, 768, (t % 24) * 32, (t / 24) * 32, false);
    } else if (bid < 4608) {
        int t = bid - 2304;
        tconv_tile(Wfc, wfct, 768, 3072, (t % 96) * 32, (t / 96) * 32, false);
    } else if (bid < 6912) {
        int t = bid - 4608;
        tconv_tile(Wpr, wprt, 3072, 768, (t % 24) * 32, (t / 24) * 32, false);
    } else {
        int i = (bid - 6912) * 256 + threadIdx.x;
        bqkv[i] = (i < 768) ? bq[i] : (i < 1536 ? bk[i - 768] : bv[i - 1536]);
    }
}

__global__ __launch_bounds__(256) void conv_layer_k(
    const float* Wq, const float* Wk, const float* Wv, const float* Wo,
    const float* Wfc, const float* Wpr,
    const float* bq, const float* bk, const float* bv,
    ushort_t* wqkvt, ushort_t* wot, ushort_t* wfct, ushort_t* wprt,
    float* bqkv) {
    conv_body(blockIdx.x, Wq, Wk, Wv, Wo, Wfc, Wpr, bq, bk, bv,
              wqkvt, wot, wfct, wprt, bqkv);
}

// all 12 layers in one launch; grid = 12 * 6921
__global__ __launch_bounds__(256) void conv_all_k(
    const float* Wq, const float* Wk, const float* Wv, const float* Wo,
    const float* Wfc, const float* Wpr,
    const float* bq, const float* bk, const float* bv,
    ushort_t* wqkvt, ushort_t* wot, ushort_t* wfct, ushort_t* wprt,
    float* bqkv) {
    int l = blockIdx.x / 6921, bid = blockIdx.x % 6921;
    const size_t o2 = (size_t)l * 768 * 768;
    const size_t o4 = (size_t)l * 768 * 3072;
    conv_body(bid,
              Wq + o2, Wk + o2, Wv + o2, Wo + o2, Wfc + o4, Wpr + o4,
              bq + l * 768, bk + l * 768, bv + l * 768,
              wqkvt + (size_t)l * 2304 * 768, wot + o2,
              wfct + o4, wprt + o4, bqkv + l * 2304);
}

// ======== generalized deep-prefetch counted-vmcnt MFMA GEMM template ========
// BK=64; LDS slot swizzle logical^(row&7), both-sides (0 bank conflicts).
// Stage ALL loads of kt+1 (full-tile latency lead), counted vmcnt (never
// drain in loop), raw barriers, setprio. QKV: scattered epilogue.
template <int BM, int BN, int TH, int WGN,
          bool BIAS, bool GELU_, bool RES, bool OUTBF16, bool XCD, bool QKV>
__global__ __launch_bounds__(TH, 2) void gemm_pipe_k(
    const ushort_t* __restrict__ A,    // [M][K] bf16
    const ushort_t* __restrict__ Bt,   // [Npad][K] bf16
    const float* __restrict__ bias,
    const float* __restrict__ res,     // [M][N] fp32 (RES only)
    void* __restrict__ Cout,
    ushort_t* __restrict__ kdst,       // QKV only
    ushort_t* __restrict__ vdst,       // QKV only
    int M, int N, int K, int cpx, int mtiles) {
    constexpr int SA = BM * 128;
    constexpr int SB = BN * 128;
    constexpr int WM = BM / 2;
    constexpr int WN = BN / WGN;
    constexpr int FM = WM / 16;
    constexpr int FN = WN / 16;
    constexpr int RJ = TH / 8;
    constexpr int JA = BM / RJ;
    constexpr int JB = BN / RJ;
    constexpr int NL = JA + JB;
    static_assert(NL == 4 || NL == 6 || NL == 8, "vmcnt immediate");
    __shared__ char lds[2 * (SA + SB)];
    char* Abase = lds;
    char* Bbase = lds + 2 * SA;

    const int tid = threadIdx.x;
    const int lane = tid & 63;
    const int w = tid >> 6;
    const int wr = w / WGN, wc = w % WGN;
    int m0, n0;
    if (XCD) {
        int lid = ((int)blockIdx.x & 7) * cpx + ((int)blockIdx.x >> 3);
        m0 = (lid % mtiles) * BM;
        n0 = (lid / mtiles) * BN;
    } else {
        m0 = blockIdx.y * BM;
        n0 = blockIdx.x * BN;
    }

    f32x4 acc[FM][FN] = {};

    const int srowl = tid >> 3;
    const int sslot = (tid & 7) ^ (srowl & 7);
    const ushort_t* Asrc = A  + (size_t)(m0 + srowl) * K + sslot * 8;
    const ushort_t* Bsrc = Bt + (size_t)(n0 + srowl) * K + sslot * 8;

    auto stageall = [&](int d, int kt) {
        const ushort_t* As = Asrc + kt * 64;
        const ushort_t* Bs = Bsrc + kt * 64;
        #pragma unroll
        for (int j = 0; j < JA; ++j)
            gload16(As + (size_t)(j * RJ) * K, Abase + d * SA + tid * 16 + j * (TH * 16));
        #pragma unroll
        for (int j = 0; j < JB; ++j)
            gload16(Bs + (size_t)(j * RJ) * K, Bbase + d * SB + tid * 16 + j * (TH * 16));
    };
    auto readA = [&](int d, int m, int ks) -> bf16x8 {
        int rl = wr * WM + m * 16 + (lane & 15);
        int s  = ks * 4 + (lane >> 4);
        return *(const bf16x8*)(Abase + d * SA + rl * 128 + ((s ^ (rl & 7)) << 4));
    };
    auto readB = [&](int d, int n, int ks) -> bf16x8 {
        int rl = wc * WN + n * 16 + (lane & 15);
        int s  = ks * 4 + (lane >> 4);
        return *(const bf16x8*)(Bbase + d * SB + rl * 128 + ((s ^ (rl & 7)) << 4));
    };

    const int nt = K >> 6;
    stageall(0, 0);
    for (int kt = 0; kt < nt; ++kt) {
        const int d = kt & 1;
        if (kt + 1 < nt) {
            stageall(d ^ 1, kt + 1);
            if constexpr (NL == 8)      asm volatile("s_waitcnt vmcnt(8)" ::: "memory");
            else if constexpr (NL == 6) asm volatile("s_waitcnt vmcnt(6)" ::: "memory");
            else                        asm volatile("s_waitcnt vmcnt(4)" ::: "memory");
        } else {
            asm volatile("s_waitcnt vmcnt(0)" ::: "memory");
        }
        __builtin_amdgcn_s_barrier();
        asm volatile("" ::: "memory");

        bf16x8 bfr[FN][2];
        #pragma unroll
        for (int n = 0; n < FN; ++n) {
            bfr[n][0] = readB(d, n, 0);
            bfr[n][1] = readB(d, n, 1);
        }
        __builtin_amdgcn_s_setprio(1);
        #pragma unroll
        for (int m = 0; m < FM; ++m) {
            bf16x8 a0 = readA(d, m, 0);
            bf16x8 a1 = readA(d, m, 1);
            #pragma unroll
            for (int n = 0; n < FN; ++n) {
                acc[m][n] = __builtin_amdgcn_mfma_f32_16x16x32_bf16(
                    a0, bfr[n][0], acc[m][n], 0, 0, 0);
                acc[m][n] = __builtin_amdgcn_mfma_f32_16x16x32_bf16(
                    a1, bfr[n][1], acc[m][n], 0, 0, 0);
            }
        }
        __builtin_amdgcn_s_setprio(0);
        asm volatile("" ::: "memory");
        __builtin_amdgcn_s_barrier();
    }

    const int r0 = (lane >> 4) * 4, c0 = lane & 15;
    if constexpr (QKV) {
        const int region = n0 / 768;
        #pragma unroll
        for (int m = 0; m < FM; ++m)
            #pragma unroll
            for (int n = 0; n < FN; ++n) {
                int col = n0 + wc * WN + n * 16 + c0;
                int row0 = m0 + wr * WM + m * 16 + r0;
                float vv[4];
                #pragma unroll
                for (int q = 0; q < 4; ++q) vv[q] = acc[m][n][q] + bias[col];
                if (region == 0) {
                    #pragma unroll
                    for (int q = 0; q < 4; ++q)
                        ((ushort_t*)Cout)[(size_t)(row0 + q) * 768 + col] = f2bf(vv[q]);
                } else if (region == 1) {
                    int ck = col - 768, h = ck >> 6, dd = ck & 63;
                    #pragma unroll
                    for (int q = 0; q < 4; ++q) {
                        int row = row0 + q;
                        kdst[(((size_t)(row >> 10) * Hn + h) * Tn + (row & 1023)) * 64 + dd]
                            = f2bf(vv[q]);
                    }
                } else {
                    int cv = col - 1536, h = cv >> 6, dd = cv & 63;
                    int bb = row0 >> 10, tok = row0 & 1023;
                    ushort4 pk;
                    pk.x = f2bf(vv[0]); pk.y = f2bf(vv[1]);
                    pk.z = f2bf(vv[2]); pk.w = f2bf(vv[3]);
                    *(ushort4*)&vdst[(((size_t)bb * Hn + h) * 64 + dd) * Tn + tok] = pk;
                }
            }
        return;
    }
    #pragma unroll
    for (int m = 0; m < FM; ++m)
        #pragma unroll
        for (int n = 0; n < FN; ++n) {
            int col = n0 + wc * WN + n * 16 + c0;
            if (col < N) {
                #pragma unroll
                for (int q = 0; q < 4; ++q) {
                    int row = m0 + wr * WM + m * 16 + r0 + q;
                    float v = acc[m][n][q];
                    if (BIAS) v += bias[col];
                    if (GELU_) v = gelu_f(v);
                    if (RES) v += res[(size_t)row * N + col];
                    if (OUTBF16) ((ushort_t*)Cout)[(size_t)row * N + col] = f2bf(v);
                    else         ((float*)Cout)[(size_t)row * N + col] = v;
                }
            }
        }
}

// ------- MFMA flash attention (T14 async-stage: preload kt+1 to regs) -------
__global__ __launch_bounds__(256) void attn_mfma_k(
    const ushort_t* __restrict__ qb,
    const ushort_t* __restrict__ kpb,
    const ushort_t* __restrict__ vtb,
    ushort_t* __restrict__ yb) {
    __shared__ ushort_t Ks[64][72];
    __shared__ ushort_t Vt[64][72];
    __shared__ ushort_t Pl[4][16][72];
    const int chunk = (Tn / 64 - 1) - blockIdx.x;
    const int h = blockIdx.y, b = blockIdx.z;
    const int tid = threadIdx.x, lane = tid & 63, w = tid >> 6;
    const int c = lane & 15, g = lane >> 4;
    const int qrow0 = chunk * 64 + w * 16;

    const ushort_t* qp = qb + (size_t)(b * Tn + qrow0 + c) * Cdim + h * 64 + g * 8;
    bf16x8 qa0 = *(const bf16x8*)qp;
    bf16x8 qa1 = *(const bf16x8*)(qp + 32);

    f32x4 accO[4] = {};
    float mrun[4], lrun[4];
    #pragma unroll
    for (int q = 0; q < 4; ++q) { mrun[q] = -1e30f; lrun[q] = 0.0f; }

    const int skey = tid >> 2, sd0 = (tid & 3) * 16;
    const ushort_t* ksrc = kpb + ((size_t)(b * Hn + h) * Tn + skey) * 64 + sd0;
    const int vd = tid >> 2, vseg = tid & 3;
    const ushort_t* vsrc = vtb + ((size_t)(b * Hn + h) * 64 + vd) * Tn + vseg * 16;
    ushort_t* KsW = &Ks[skey][sd0];
    ushort_t* VtW = &Vt[vd][vseg * 16];

    uint4 kr0, kr1, vr0, vr1;
    auto loadt = [&](int kt) {
        const ushort_t* kp = ksrc + (size_t)kt * 64 * 64;
        kr0 = *(const uint4*)kp;
        kr1 = *(const uint4*)(kp + 8);
        const ushort_t* vp = vsrc + kt * 64;
        vr0 = *(const uint4*)vp;
        vr1 = *(const uint4*)(vp + 8);
    };

    const int ntiles = chunk + 1;
    loadt(0);
    for (int kt = 0; kt < ntiles; ++kt) {
        __syncthreads();
        *(uint4*)KsW       = kr0;
        *(uint4*)(KsW + 8) = kr1;
        *(uint4*)VtW       = vr0;
        *(uint4*)(VtW + 8) = vr1;
        __syncthreads();
        if (kt + 1 < ntiles) loadt(kt + 1);

        f32x4 sf[4];
        #pragma unroll
        for (int nk = 0; nk < 4; ++nk) {
            bf16x8 kf0 = *(const bf16x8*)&Ks[nk * 16 + c][g * 8];
            bf16x8 kf1 = *(const bf16x8*)&Ks[nk * 16 + c][g * 8 + 32];
            f32x4 z = {};
            z = __builtin_amdgcn_mfma_f32_16x16x32_bf16(qa0, kf0, z, 0, 0, 0);
            z = __builtin_amdgcn_mfma_f32_16x16x32_bf16(qa1, kf1, z, 0, 0, 0);
            sf[nk] = z;
        }
        float pmax[4] = {-1e30f, -1e30f, -1e30f, -1e30f};
        #pragma unroll
        for (int nk = 0; nk < 4; ++nk) {
            int key = kt * 64 + nk * 16 + c;
            #pragma unroll
            for (int q = 0; q < 4; ++q) {
                float sv = sf[nk][q];
                int row = qrow0 + g * 4 + q;
                sv = (key > row) ? -1e30f : sv;
                sf[nk][q] = sv;
                pmax[q] = fmaxf(pmax[q], sv);
            }
        }
        #pragma unroll
        for (int q = 0; q < 4; ++q)
            #pragma unroll
            for (int off = 1; off < 16; off <<= 1)
                pmax[q] = fmaxf(pmax[q], __shfl_xor(pmax[q], off));
        float corr[4], psum[4];
        #pragma unroll
        for (int q = 0; q < 4; ++q) {
            float mn = fmaxf(mrun[q], pmax[q]);
            corr[q] = __expf((mrun[q] - mn) * 0.125f);
            mrun[q] = mn;
            psum[q] = 0.0f;
        }
        #pragma unroll
        for (int nk = 0; nk < 4; ++nk)
            #pragma unroll
            for (int q = 0; q < 4; ++q) {
                float p = __expf((sf[nk][q] - mrun[q]) * 0.125f);
                psum[q] += p;
                Pl[w][g * 4 + q][nk * 16 + c] = f2bf(p);
            }
        #pragma unroll
        for (int q = 0; q < 4; ++q) {
            #pragma unroll
            for (int off = 1; off < 16; off <<= 1)
                psum[q] += __shfl_xor(psum[q], off);
            lrun[q] = lrun[q] * corr[q] + psum[q];
        }
        #pragma unroll
        for (int ni = 0; ni < 4; ++ni)
            #pragma unroll
            for (int q = 0; q < 4; ++q)
                accO[ni][q] *= corr[q];

        asm volatile("" ::: "memory");
        bf16x8 pa0 = *(const bf16x8*)&Pl[w][c][g * 8];
        bf16x8 pa1 = *(const bf16x8*)&Pl[w][c][g * 8 + 32];
        #pragma unroll
        for (int ni = 0; ni < 4; ++ni) {
            bf16x8 bv0 = *(const bf16x8*)&Vt[ni * 16 + c][g * 8];
            bf16x8 bv1 = *(const bf16x8*)&Vt[ni * 16 + c][g * 8 + 32];
            accO[ni] = __builtin_amdgcn_mfma_f32_16x16x32_bf16(pa0, bv0, accO[ni], 0, 0, 0);
            accO[ni] = __builtin_amdgcn_mfma_f32_16x16x32_bf16(pa1, bv1, accO[ni], 0, 0, 0);
        }
    }

    #pragma unroll
    for (int q = 0; q < 4; ++q) {
        float inv = 1.0f / lrun[q];
        ushort_t* yr = yb + (size_t)(b * Tn + qrow0 + g * 4 + q) * Cdim + h * 64;
        #pragma unroll
        for (int ni = 0; ni < 4; ++ni)
            yr[ni * 16 + c] = f2bf(accO[ni][q] * inv);
    }
}

extern "C" void kernel_launch(void* const* d_in, const int* in_sizes, int n_in,
                              void* d_out, int out_size, void* d_ws, size_t ws_size,
                              hipStream_t stream) {
    const int*   idx  = (const int*)d_in[0];
    const float* wte  = (const float*)d_in[1];
    const float* wpe  = (const float*)d_in[2];
    const float* ln1w = (const float*)d_in[3];
    const float* ln1b = (const float*)d_in[4];
    const float* Wq   = (const float*)d_in[5];
    const float* bq   = (const float*)d_in[6];
    const float* Wk   = (const float*)d_in[7];
    const float* bk   = (const float*)d_in[8];
    const float* Wv   = (const float*)d_in[9];
    const float* bv   = (const float*)d_in[10];
    const float* Wo   = (const float*)d_in[11];
    const float* bo   = (const float*)d_in[12];
    const float* ln2w = (const float*)d_in[13];
    const float* ln2b = (const float*)d_in[14];
    const float* Wfc  = (const float*)d_in[15];
    const float* bfc  = (const float*)d_in[16];
    const float* Wpr  = (const float*)d_in[17];
    const float* bpr  = (const float*)d_in[18];
    const float* lnfw = (const float*)d_in[19];
    const float* lnfb = (const float*)d_in[20];
    const float* Wlm  = (const float*)d_in[21];
    float* out = (float*)d_out;

    const int M = Mrows;                        // 2048
    const int V = out_size / M;                 // 50257
    const int Vpad = ((V + 255) / 256) * 256;   // 50432

    const size_t SZ_QKV = (size_t)2304 * 768;
    const size_t SZ_O   = (size_t)768 * 768;
    const size_t SZ_FC  = (size_t)3072 * 768;
    const size_t SZ_PR  = (size_t)768 * 3072;
    const size_t SZ_L   = SZ_QKV + SZ_O + SZ_FC + SZ_PR;

    float*    x     = (float*)d_ws;                       // M*C fp32
    float*    bqkvb = x + (size_t)M * Cdim;               // 12*2304 fp32
    ushort_t* qb    = (ushort_t*)(bqkvb + 12 * 2304);     // M*768
    ushort_t* kpb   = qb + (size_t)M * Cdim;              // [B*H][Tn][64]
    ushort_t* vtb   = kpb + (size_t)Bn * Hn * Tn * 64;    // [B*H][64][Tn]
    ushort_t* hb    = vtb + (size_t)Bn * Hn * 64 * Tn;
    ushort_t* yb    = hb + (size_t)M * Cdim;
    ushort_t* mid   = yb + (size_t)M * Cdim;              // M*3072
    ushort_t* wlmt  = mid + (size_t)M * 3072;             // [Vpad][768]
    ushort_t* wbase = wlmt + (size_t)Vpad * Cdim;         // layer weights

    const size_t used_common = (size_t)((char*)wbase - (char*)d_ws);
    const bool big = ws_size >= used_common + 12 * SZ_L * sizeof(ushort_t);

    embed_k<<<(M * Cdim) / 256, 256, 0, stream>>>(idx, wte, wpe, x);
    wconv_k<<<dim3(Vpad / 32, 24), 256, 0, stream>>>(Wlm, wlmt, Cdim, V);

    ushort_t* wqkvt0 = wbase;
    ushort_t* wot0   = wqkvt0 + SZ_QKV;
    ushort_t* wfct0  = wot0 + SZ_O;
    ushort_t* wprt0  = wfct0 + SZ_FC;

    if (big) {
        ushort_t* qkvt_all = wbase;
        ushort_t* ot_all   = qkvt_all + 12 * SZ_QKV;
        ushort_t* fct_all  = ot_all + 12 * SZ_O;
        ushort_t* prt_all  = fct_all + 12 * SZ_FC;
        conv_all_k<<<12 * 6921, 256, 0, stream>>>(
            Wq, Wk, Wv, Wo, Wfc, Wpr, bq, bk, bv,
            qkvt_all, ot_all, fct_all, prt_all, bqkvb);
        for (int l = 0; l < Ln; ++l) {
            ushort_t* wqkvt = qkvt_all + (size_t)l * SZ_QKV;
            ushort_t* wot   = ot_all   + (size_t)l * SZ_O;
            ushort_t* wfct  = fct_all  + (size_t)l * SZ_FC;
            ushort_t* wprt  = prt_all  + (size_t)l * SZ_PR;
            float*    bqkv  = bqkvb + l * 2304;
            ln_k<<<M, 256, 0, stream>>>(x, ln1w + l * Cdim, ln1b + l * Cdim, hb);
            gemm_pipe_k<128, 64, 256, 2, true, false, false, true, false, true>
                <<<dim3(36, 16), 256, 0, stream>>>(
                hb, wqkvt, bqkv, nullptr, qb, kpb, vtb, M, 2304, Cdim, 0, 0);
            attn_mfma_k<<<dim3(16, Hn, Bn), 256, 0, stream>>>(qb, kpb, vtb, yb);
            gemm_pipe_k<64, 64, 256, 2, true, false, true, false, false, false>
                <<<dim3(12, 32), 256, 0, stream>>>(
                yb, wot, bo + l * Cdim, x, x, nullptr, nullptr, M, Cdim, Cdim, 0, 0);
            ln_k<<<M, 256, 0, stream>>>(x, ln2w + l * Cdim, ln2b + l * Cdim, hb);
            gemm_pipe_k<128, 64, 256, 2, true, true, false, true, false, false>
                <<<dim3(48, 16), 256, 0, stream>>>(
                hb, wfct, bfc + (size_t)l * 4 * Cdim, nullptr, mid,
                nullptr, nullptr, M, 3072, Cdim, 0, 0);
            gemm_pipe_k<64, 64, 256, 2, true, false, true, false, false, false>
                <<<dim3(12, 32), 256, 0, stream>>>(
                mid, wprt, bpr + l * Cdim, x, x, nullptr, nullptr, M, Cdim, 3072, 0, 0);
        }
    } else {
        for (int l = 0; l < Ln; ++l) {
            const size_t wo2 = (size_t)l * Cdim * Cdim;
            const size_t wo4 = (size_t)l * Cdim * 4 * Cdim;
            conv_layer_k<<<6921, 256, 0, stream>>>(
                Wq + wo2, Wk + wo2, Wv + wo2, Wo + wo2, Wfc + wo4, Wpr + wo4,
                bq + l * Cdim, bk + l * Cdim, bv + l * Cdim,
                wqkvt0, wot0, wfct0, wprt0, bqkvb);
            ln_k<<<M, 256, 0, stream>>>(x, ln1w + l * Cdim, ln1b + l * Cdim, hb);
            gemm_pipe_k<128, 64, 256, 2, true, false, false, true, false, true>
                <<<dim3(36, 16), 256, 0, stream>>>(
                hb, wqkvt0, bqkvb, nullptr, qb, kpb, vtb, M, 2304, Cdim, 0, 0);
            attn_mfma_k<<<dim3(16, Hn, Bn), 256, 0, stream>>>(qb, kpb, vtb, yb);
            gemm_pipe_k<64, 64, 256, 2, true, false, true, false, false, false>
                <<<dim3(12, 32), 256, 0, stream>>>(
                yb, wot0, bo + l * Cdim, x, x, nullptr, nullptr, M, Cdim, Cdim, 0, 0);
            ln_k<<<M, 256, 0, stream>>>(x, ln2w + l * Cdim, ln2b + l * Cdim, hb);
            gemm_pipe_k<128, 64, 256, 2, true, true, false, true, false, false>
                <<<dim3(48, 16), 256, 0, stream>>>(
                hb, wfct0, bfc + (size_t)l * 4 * Cdim, nullptr, mid,
                nullptr, nullptr, M, 3072, Cdim, 0, 0);
            gemm_pipe_k<64, 64, 256, 2, true, false, true, false, false, false>
                <<<dim3(12, 32), 256, 0, stream>>>(
                mid, wprt0, bpr + l * Cdim, x, x, nullptr, nullptr, M, Cdim, 3072, 0, 0);
        }
    }

    ln_k<<<M, 256, 0, stream>>>(x, lnfw, lnfb, hb);
    // LM head: round-13 optimum -- 128x128 tiles, XCD strips (6304 = 8 x 788,
    // M-fastest, mtiles=16), regular fp32 stores.
    const int nblk = 16 * (Vpad / 128);         // 6304
    gemm_pipe_k<128, 128, 256, 2, false, false, false, false, true, false>
        <<<nblk, 256, 0, stream>>>(
        hb, wlmt, nullptr, nullptr, out, nullptr, nullptr, M, V, Cdim, nblk / 8, 16);
}